// Round 12
// baseline (62.179 us; speedup 1.0000x reference)
//
#include <hip/hip_runtime.h>
#include <math.h>

#define N_BINS 256
#define TAU 0.01f
#define EPS 1e-10f
#define HW (512*512)
#define QF 2041           // fine levels; QF-1 = 2040 = 8*255 so t_q - b_j = (q-8j)/2040
#define QS2 2048
#define PH 8              // phases (q mod 8)
#define MWIN2 104         // |q-8j| <= 104 -> dropped weight exp(-13) ~ 2e-6
#define WTAB2 209
#define WPADN2 216        // 8*27, zero-padded tail
#define NP 27             // taps per phase
#define CFP_STRIDE2 285   // row length (>=282), %32=29 -> banks spread
#define NPART 128         // K1 partial soft-hists per batch
#define REDS 260          // red row stride (floats), 16B-aligned rows

typedef float vfloat4 __attribute__((ext_vector_type(4)));  // native vec for nontemporal

// -------- K1: fine hist -> register-blocked conv -> 256-float soft partial --------
// grid (128,B) x 512 thr, ~19 KB LDS -> 2 blocks/CU co-resident (16 waves/CU).
__global__ __launch_bounds__(512) void hist_conv_kernel(const float* __restrict__ x,
                                                        float* __restrict__ partT) {
    __shared__ float cfp[PH * CFP_STRIDE2];                           // 8.9 KB
    __shared__ union { unsigned int lh[QS2]; float ph[N_BINS * 9]; } U;  // 9 KB
    __shared__ float wtE[WPADN2];
    const int b   = blockIdx.y;
    const int s   = blockIdx.x;
    const int tid = threadIdx.x;
    const int r   = tid & 7;
    const int t   = tid >> 3;        // 0..63 -> 4 bins each

    for (int i = tid; i < QS2; i += 512) U.lh[i] = 0u;
    for (int i = tid; i < PH * CFP_STRIDE2; i += 512) cfp[i] = 0.f;
    for (int i = tid; i < WPADN2; i += 512) {
        const float d = (float)(i - MWIN2) * (1.0f / 2040.f);
        wtE[i] = (i < WTAB2) ? __expf(-d * d * (1.0f / (2.0f * TAU * TAU))) : 0.f;
    }
    __syncthreads();

    // 2048 px/block: one float4 per thread
    {
        const float4 v = ((const float4*)(x + (size_t)b * HW + (size_t)s * 2048))[tid];
        int q0 = __float2int_rn(v.x * 2040.f);
        int q1 = __float2int_rn(v.y * 2040.f);
        int q2 = __float2int_rn(v.z * 2040.f);
        int q3 = __float2int_rn(v.w * 2040.f);
        q0 = min(max(q0, 0), QF - 1); q1 = min(max(q1, 0), QF - 1);
        q2 = min(max(q2, 0), QF - 1); q3 = min(max(q3, 0), QF - 1);
        atomicAdd(&U.lh[q0], 1u); atomicAdd(&U.lh[q1], 1u);
        atomicAdd(&U.lh[q2], 1u); atomicAdd(&U.lh[q3], 1u);
    }
    __syncthreads();

    // scatter fine hist phase-transposed into cfp (pads stay zero)
#pragma unroll
    for (int k = 0; k < 4; ++k) {
        const int q = k * 512 + tid;
        cfp[(q & 7) * CFP_STRIDE2 + (q >> 3) + 13] = (float)U.lh[q];
    }
    __syncthreads();

    // conv: hist[j] = sum_p sum_r wtE[8p+r] * cfp[r][j+p]; thread (r,t): bins 4t..4t+3
    {
        float creg[30];
        const float* cbase = &cfp[r * CFP_STRIDE2 + 4 * t];
#pragma unroll
        for (int k = 0; k < 30; ++k) creg[k] = cbase[k];
        float acc[4] = {0.f, 0.f, 0.f, 0.f};
#pragma unroll
        for (int p = 0; p < NP; ++p) {
            const float w = wtE[8 * p + r];
#pragma unroll
            for (int uu = 0; uu < 4; ++uu) acc[uu] += w * creg[uu + p];
        }
#pragma unroll
        for (int uu = 0; uu < 4; ++uu) U.ph[(4 * t + uu) * 9 + r] = acc[uu];
    }
    __syncthreads();

    // phase-reduce -> coalesced store: partT[b][s][bin]
    if (tid < N_BINS) {
        float hv = 0.f;
#pragma unroll
        for (int rr = 0; rr < 8; ++rr) hv += U.ph[tid * 9 + rr];
        partT[((size_t)b * NPART + s) * N_BINS + tid] = hv;
    }
}

// -------- K2: coalesced reduce -> scan -> LUT -> equalize --------
// grid (64,B) x 512 thr. Dispatch boundary = the device-wide barrier.
__global__ __launch_bounds__(512) void lut_equalize_kernel(const float* __restrict__ x,
                                                           const float* __restrict__ partT,
                                                           float* __restrict__ out) {
    __shared__ float Tl[QS2];                        // 8 KB
    __shared__ float wtE[WPADN2];
    __shared__ float cdfnp[288];
    __shared__ float onesp[288];
    __shared__ __align__(16) float red[8 * REDS];    // 8.3 KB
    __shared__ float wsum[4];
    __shared__ float h0s;
    const int b    = blockIdx.y;
    const int s    = blockIdx.x;
    const int tid  = threadIdx.x;
    const int r    = tid & 7;
    const int t    = tid >> 3;       // 0..63
    const int wv   = tid >> 6;       // wave 0..7
    const int lane = tid & 63;

    for (int i = tid; i < 288; i += 512) {
        cdfnp[i] = 0.f;
        onesp[i] = (i >= 13 && i < 269) ? 1.f : 0.f;
    }
    for (int i = tid; i < WPADN2; i += 512) {
        const float d = (float)(i - MWIN2) * (1.0f / 2040.f);
        wtE[i] = (i < WTAB2) ? __expf(-d * d * (1.0f / (2.0f * TAU * TAU))) : 0.f;
    }

    // pixel loads issued early (independent of the reduction)
    const float4* xb = (const float4*)(x + (size_t)b * HW + (size_t)s * 4096);
    float4 px[2];
#pragma unroll
    for (int i = 0; i < 2; ++i) px[i] = xb[i * 512 + tid];

    // reduce 128x256 partials: wave wv sums rows 16wv..16wv+15 (lane-contiguous float4)
    {
        const float4* base4 = (const float4*)(partT + (size_t)b * NPART * N_BINS);
        float4 a4 = make_float4(0.f, 0.f, 0.f, 0.f);
#pragma unroll
        for (int rr = 0; rr < 16; ++rr) {
            const float4 v = base4[(size_t)(16 * wv + rr) * 64 + lane];
            a4.x += v.x; a4.y += v.y; a4.z += v.z; a4.w += v.w;
        }
        ((float4*)&red[wv * REDS])[lane] = a4;
    }
    __syncthreads();

    // cross-wave reduce + wave-shuffle scan over 256 bins + cdf normalization
    float val = 0.f, hv = 0.f;
    if (tid < N_BINS) {
#pragma unroll
        for (int w2 = 0; w2 < 8; ++w2) hv += red[w2 * REDS + tid];
        val = hv;
#pragma unroll
        for (int d = 1; d < 64; d <<= 1) {
            const float n = __shfl_up(val, (unsigned)d, 64);
            if (lane >= d) val += n;
        }
        if (lane == 63) wsum[tid >> 6] = val;
        if (tid == 0) h0s = hv;
    }
    __syncthreads();
    if (tid < N_BINS) {
        float prefix = 0.f, total = 0.f;
#pragma unroll
        for (int w2 = 0; w2 < 4; ++w2) {
            const float ws = wsum[w2];
            if (w2 < (tid >> 6)) prefix += ws;
            total += ws;
        }
        val += prefix;
        const float inv  = 1.0f / (total + EPS);
        const float cdf0 = h0s * inv;
        cdfnp[tid + 13] = (val * inv - cdf0) / (1.0f - cdf0 + EPS);
    }
    __syncthreads();

    // output LUT: thread (r,t) computes T[8u+r] for u = 4t..4t+3
    {
        float creg[30], oreg[30];
        const int base = 4 * t;
#pragma unroll
        for (int k = 0; k < 30; ++k) { creg[k] = cdfnp[base + k]; oreg[k] = onesp[base + k]; }
        float acc[4] = {0.f, 0.f, 0.f, 0.f}, sw[4] = {0.f, 0.f, 0.f, 0.f};
#pragma unroll
        for (int p = 0; p < NP; ++p) {
            const float w = wtE[8 * p + r];
#pragma unroll
            for (int uu = 0; uu < 4; ++uu) {
                const int k = uu - p + 26;   // in [0,30)
                acc[uu] += w * creg[k];
                sw[uu]  += w * oreg[k];
            }
        }
#pragma unroll
        for (int uu = 0; uu < 4; ++uu)
            Tl[8 * (4 * t + uu) + r] = acc[uu] / (sw[uu] + EPS);
    }
    __syncthreads();

    // equalize register-held pixels via LUT lerp; non-temporal out stores
    vfloat4* ob = (vfloat4*)(out + (size_t)b * HW + (size_t)s * 4096);
#pragma unroll
    for (int i = 0; i < 2; ++i) {
        const float4 v = px[i];
        const float vv[4] = {v.x, v.y, v.z, v.w};
        float res[4];
#pragma unroll
        for (int k2 = 0; k2 < 4; ++k2) {
            const float u = vv[k2] * 2040.f;
            int q = (int)u;
            q = min(max(q, 0), QF - 2);
            const float frac = u - (float)q;
            const float t0 = Tl[q], t1 = Tl[q + 1];
            res[k2] = fmaf(frac, t1 - t0, t0);
        }
        vfloat4 o;
        o.x = res[0]; o.y = res[1]; o.z = res[2]; o.w = res[3];
        __builtin_nontemporal_store(o, &ob[i * 512 + tid]);
    }
}

extern "C" void kernel_launch(void* const* d_in, const int* in_sizes, int n_in,
                              void* d_out, int out_size, void* d_ws, size_t ws_size,
                              hipStream_t stream) {
    const float* x = (const float*)d_in[0];
    float* out     = (float*)d_out;
    const int B    = in_sizes[0] / HW;   // = 4

    float* partT = (float*)d_ws;         // B*128*256 floats = 512 KB, plain stores (no memset)

    hist_conv_kernel<<<dim3(NPART, B), 512, 0, stream>>>(x, partT);
    lut_equalize_kernel<<<dim3(64, B), 512, 0, stream>>>(x, partT, out);
}